// Round 9
// baseline (218.035 us; speedup 1.0000x reference)
//
#include <hip/hip_runtime.h>

#define BATCH 32768
#define SEQ 512
#define TPL 8          // timesteps per lane (64 lanes * 8 = 512)
#define EPS 1e-8f
#define ROWS 4         // rows per wave, software-pipelined 1-deep

typedef float floatx4 __attribute__((ext_vector_type(4)));

// v10 = v9 policy (ALL-nt reads, vectorized values via shfl, normal stores)
//     x v4 structure (4 rows/wave, 1-deep register double-buffer pipeline).
//
// r8 evidence: nt-reads cut dur 86->72->56.5us at CONSTANT fetch (100MB) ->
// wins are cache-allocation politics, not bytes. At 56.5us nothing is
// saturated (VALU 38%, HBM 38%, occ 66%): classic sustained-MLP deficit --
// each wave's 10KB load burst lands, then ~2k cycles of compute with zero
// memory demand. v4 tested this exact fix and nulled -- but in the OLD
// regime where L2-way thrash capped service at 2TB/s regardless of demand.
// That gate is gone. Retest demand-side pipelining in the new regime
// (prereq-gated combo, same shape as the v7->v9 ladder). Side win: lambda
// tanh prep amortized 4x (wave count 32768->8192), cutting the ~21us VALU
// floor toward ~8us.

struct RowBuf {
    floatx4 va, vb;      // values[row][t0..t0+8) (aligned pair, shifted later)
    floatx4 ra, rb;      // rewards
    floatx4 da, db;      // dones
    float   vlast;       // values[row][SEQ]
};

__device__ __forceinline__ void load_row(const float* __restrict__ values,
                                         const float* __restrict__ rewards,
                                         const float* __restrict__ dones,
                                         int row, int t0, RowBuf& b) {
    const float* __restrict__ vrow = values  + (size_t)row * (SEQ + 1);
    const float* __restrict__ rrow = rewards + (size_t)row * SEQ + t0;
    const float* __restrict__ drow = dones   + (size_t)row * SEQ + t0;
    b.va = __builtin_nontemporal_load((const floatx4*)(vrow + t0));
    b.vb = __builtin_nontemporal_load((const floatx4*)(vrow + t0 + 4));
    b.ra = __builtin_nontemporal_load((const floatx4*)(rrow));
    b.rb = __builtin_nontemporal_load((const floatx4*)(rrow + 4));
    b.da = __builtin_nontemporal_load((const floatx4*)(drow));
    b.db = __builtin_nontemporal_load((const floatx4*)(drow + 4));
    b.vlast = __builtin_nontemporal_load(vrow + SEQ);   // wave-uniform line
}

__device__ __forceinline__ void compute_store(float* __restrict__ out,
                                              int row, int t0, int lane,
                                              const float gl[TPL],
                                              const float gl1[TPL],
                                              const RowBuf& bu) {
    // vj[j] = vrow[1 + t0 + j]: shift aligned pair left one element; element 8
    // comes from the next lane (shfl); lane 63 patches with vlast (=vrow[512]).
    const float nx = __shfl_down(bu.va.x, 1, 64);
    const float vj[TPL] = {bu.va.y, bu.va.z, bu.va.w, bu.vb.x,
                           bu.vb.y, bu.vb.z, bu.vb.w,
                           (lane == 63) ? bu.vlast : nx};
    const float rj[TPL] = {bu.ra.x, bu.ra.y, bu.ra.z, bu.ra.w,
                           bu.rb.x, bu.rb.y, bu.rb.z, bu.rb.w};
    const float dj[TPL] = {bu.da.x, bu.da.y, bu.da.z, bu.da.w,
                           bu.db.x, bu.db.y, bu.db.z, bu.db.w};

    // per-lane affine summary (t descending):
    // a_t = gamma*lam*(1-d), b_t = r + gamma*(1-lam)*(1-d)*v_{t+1}
    float a[TPL], b[TPL];
    float A = 1.f, Bv = 0.f;
    #pragma unroll
    for (int j = TPL - 1; j >= 0; --j) {
        const float e = 1.f - dj[j];
        a[j] = gl[j] * e;
        b[j] = fmaf(gl1[j] * e, vj[j], rj[j]);
        Bv = fmaf(a[j], Bv, b[j]);
        A  = a[j] * A;
    }

    // wave-level inclusive suffix scan of (A,B)
    #pragma unroll
    for (int dlt = 1; dlt < 64; dlt <<= 1) {
        const float oA = __shfl_down(A, dlt, 64);
        const float oB = __shfl_down(Bv, dlt, 64);
        if (lane + dlt < 64) {                // compose(mine, downstream)
            Bv = fmaf(A, oB, Bv);
            A  = A * oA;
        }
    }
    float EA = __shfl_down(A, 1, 64);
    float EB = __shfl_down(Bv, 1, 64);
    if (lane == 63) { EA = 1.f; EB = 0.f; }

    float ret = fmaf(EA, bu.vlast, EB);       // boundary ret for this lane

    float o[TPL];
    #pragma unroll
    for (int j = TPL - 1; j >= 0; --j) {
        ret = fmaf(a[j], ret, b[j]);
        o[j] = ret;
    }
    float* __restrict__ orow = out + (size_t)row * SEQ + t0;
    *(float4*)(orow)     = make_float4(o[0], o[1], o[2], o[3]);
    *(float4*)(orow + 4) = make_float4(o[4], o[5], o[6], o[7]);
}

__global__ void __launch_bounds__(256)
glr_wave_scan10(const float* __restrict__ values,
                const float* __restrict__ rewards,
                const float* __restrict__ dones,
                const float* __restrict__ raw_gamma,
                const float* __restrict__ raw_lambd,
                float* __restrict__ out) {
    const int lane = threadIdx.x & 63;
    const int wv   = threadIdx.x >> 6;
    const int wave = blockIdx.x * 4 + wv;     // 0..8191
    const int row0 = wave * ROWS;             // 4 consecutive rows per wave
    const int t0   = lane * TPL;

    RowBuf A, B;
    load_row(values, rewards, dones, row0 + 0, t0, A);   // issue first

    // lambda/gamma prep overlaps row0's loads (row-invariant, once per wave)
    const float gamma = fmaxf(tanhf(raw_gamma[0]), EPS);
    const float4 l4a = *(const float4*)(raw_lambd + t0);
    const float4 l4b = *(const float4*)(raw_lambd + t0 + 4);
    const float lr[TPL] = {l4a.x, l4a.y, l4a.z, l4a.w,
                           l4b.x, l4b.y, l4b.z, l4b.w};
    float gl[TPL], gl1[TPL];
    #pragma unroll
    for (int j = 0; j < TPL; ++j) {
        const float lm = fmaxf(tanhf(lr[j]), EPS);
        gl[j]  = gamma * lm;          // a_t / (1-d)
        gl1[j] = gamma * (1.f - lm);  // (b_t - r_t) / ((1-d)*v)
    }

    // fully unrolled 1-deep pipeline, named buffers only (no runtime indexing)
    load_row(values, rewards, dones, row0 + 1, t0, B);
    compute_store(out, row0 + 0, t0, lane, gl, gl1, A);
    load_row(values, rewards, dones, row0 + 2, t0, A);
    compute_store(out, row0 + 1, t0, lane, gl, gl1, B);
    load_row(values, rewards, dones, row0 + 3, t0, B);
    compute_store(out, row0 + 2, t0, lane, gl, gl1, A);
    compute_store(out, row0 + 3, t0, lane, gl, gl1, B);
}

extern "C" void kernel_launch(void* const* d_in, const int* in_sizes, int n_in,
                              void* d_out, int out_size, void* d_ws, size_t ws_size,
                              hipStream_t stream) {
    const float* values    = (const float*)d_in[0];
    const float* rewards   = (const float*)d_in[1];
    const float* dones     = (const float*)d_in[2];
    const float* raw_gamma = (const float*)d_in[3];
    const float* raw_lambd = (const float*)d_in[4];
    float* out = (float*)d_out;

    const int block = 256;                    // 4 waves/block
    const int grid  = BATCH / (4 * ROWS);     // 2048 blocks
    glr_wave_scan10<<<grid, block, 0, stream>>>(
        values, rewards, dones, raw_gamma, raw_lambd, out);
}

// Round 10
// 216.942 us; speedup vs baseline: 1.0050x; 1.0050x over previous
//
#include <hip/hip_runtime.h>

#define BATCH 32768
#define SEQ 512
#define TPL 8          // timesteps per lane (64 lanes * 8 = 512)
#define EPS 1e-8f
#define ROWS 4         // rows per wave, software-pipelined 1-deep
#define NWAVES (BATCH / ROWS)   // 8192 waves; row stride between a wave's rows

typedef float floatx4 __attribute__((ext_vector_type(4)));

// v11 = v10 pipeline + INTERLEAVED row mapping (confound removal).
//
// r9 evidence: v10's regression (56.5->66us) decomposes as rate-flat
// (2.9 vs 3.0 TB/s) + fetch-inflated (+21MB). The pipeline's own effects
// landed (VALUBusy 38->13% = 4x tanh amortization). Suspect: the BLOCKED
// row mapping (wave owns rows 4w..4w+3) broke v9's dispatch-order address
// sweep and degraded the knife-edge MALL residency. v11 keeps the pipeline
// but maps wave w -> rows {w, w+8192, w+16384, w+24576}: at pipeline step k
// the active front is a contiguous 8192-row stripe sweeping in address
// order, byte-pattern-identical to v9 per step.
// Committed read: FETCH~100 & dur<=52 -> keep pushing; FETCH~100 & dur~56
// -> 3TB/s service ceiling confirmed across 3 structures, declare roofline;
// FETCH~120 -> mapping wasn't the inflator, revert to v9 and declare.

struct RowBuf {
    floatx4 va, vb;      // values[row][t0..t0+8) (aligned pair, shifted later)
    floatx4 ra, rb;      // rewards
    floatx4 da, db;      // dones
    float   vlast;       // values[row][SEQ]
};

__device__ __forceinline__ void load_row(const float* __restrict__ values,
                                         const float* __restrict__ rewards,
                                         const float* __restrict__ dones,
                                         int row, int t0, RowBuf& b) {
    const float* __restrict__ vrow = values  + (size_t)row * (SEQ + 1);
    const float* __restrict__ rrow = rewards + (size_t)row * SEQ + t0;
    const float* __restrict__ drow = dones   + (size_t)row * SEQ + t0;
    b.va = __builtin_nontemporal_load((const floatx4*)(vrow + t0));
    b.vb = __builtin_nontemporal_load((const floatx4*)(vrow + t0 + 4));
    b.ra = __builtin_nontemporal_load((const floatx4*)(rrow));
    b.rb = __builtin_nontemporal_load((const floatx4*)(rrow + 4));
    b.da = __builtin_nontemporal_load((const floatx4*)(drow));
    b.db = __builtin_nontemporal_load((const floatx4*)(drow + 4));
    b.vlast = __builtin_nontemporal_load(vrow + SEQ);   // wave-uniform line
}

__device__ __forceinline__ void compute_store(float* __restrict__ out,
                                              int row, int t0, int lane,
                                              const float gl[TPL],
                                              const float gl1[TPL],
                                              const RowBuf& bu) {
    // vj[j] = vrow[1 + t0 + j]: shift aligned pair left one element; element 8
    // comes from the next lane (shfl); lane 63 patches with vlast (=vrow[512]).
    const float nx = __shfl_down(bu.va.x, 1, 64);
    const float vj[TPL] = {bu.va.y, bu.va.z, bu.va.w, bu.vb.x,
                           bu.vb.y, bu.vb.z, bu.vb.w,
                           (lane == 63) ? bu.vlast : nx};
    const float rj[TPL] = {bu.ra.x, bu.ra.y, bu.ra.z, bu.ra.w,
                           bu.rb.x, bu.rb.y, bu.rb.z, bu.rb.w};
    const float dj[TPL] = {bu.da.x, bu.da.y, bu.da.z, bu.da.w,
                           bu.db.x, bu.db.y, bu.db.z, bu.db.w};

    // per-lane affine summary (t descending):
    // a_t = gamma*lam*(1-d), b_t = r + gamma*(1-lam)*(1-d)*v_{t+1}
    float a[TPL], b[TPL];
    float A = 1.f, Bv = 0.f;
    #pragma unroll
    for (int j = TPL - 1; j >= 0; --j) {
        const float e = 1.f - dj[j];
        a[j] = gl[j] * e;
        b[j] = fmaf(gl1[j] * e, vj[j], rj[j]);
        Bv = fmaf(a[j], Bv, b[j]);
        A  = a[j] * A;
    }

    // wave-level inclusive suffix scan of (A,B)
    #pragma unroll
    for (int dlt = 1; dlt < 64; dlt <<= 1) {
        const float oA = __shfl_down(A, dlt, 64);
        const float oB = __shfl_down(Bv, dlt, 64);
        if (lane + dlt < 64) {                // compose(mine, downstream)
            Bv = fmaf(A, oB, Bv);
            A  = A * oA;
        }
    }
    float EA = __shfl_down(A, 1, 64);
    float EB = __shfl_down(Bv, 1, 64);
    if (lane == 63) { EA = 1.f; EB = 0.f; }

    float ret = fmaf(EA, bu.vlast, EB);       // boundary ret for this lane

    float o[TPL];
    #pragma unroll
    for (int j = TPL - 1; j >= 0; --j) {
        ret = fmaf(a[j], ret, b[j]);
        o[j] = ret;
    }
    float* __restrict__ orow = out + (size_t)row * SEQ + t0;
    *(float4*)(orow)     = make_float4(o[0], o[1], o[2], o[3]);
    *(float4*)(orow + 4) = make_float4(o[4], o[5], o[6], o[7]);
}

__global__ void __launch_bounds__(256)
glr_wave_scan11(const float* __restrict__ values,
                const float* __restrict__ rewards,
                const float* __restrict__ dones,
                const float* __restrict__ raw_gamma,
                const float* __restrict__ raw_lambd,
                float* __restrict__ out) {
    const int lane = threadIdx.x & 63;
    const int wv   = threadIdx.x >> 6;
    const int wave = blockIdx.x * 4 + wv;     // 0..8191
    const int t0   = lane * TPL;
    // interleaved mapping: this wave's k-th row = wave + k*NWAVES
    const int row0 = wave;

    RowBuf A, B;
    load_row(values, rewards, dones, row0, t0, A);       // issue first

    // lambda/gamma prep overlaps row0's loads (row-invariant, once per wave)
    const float gamma = fmaxf(tanhf(raw_gamma[0]), EPS);
    const float4 l4a = *(const float4*)(raw_lambd + t0);
    const float4 l4b = *(const float4*)(raw_lambd + t0 + 4);
    const float lr[TPL] = {l4a.x, l4a.y, l4a.z, l4a.w,
                           l4b.x, l4b.y, l4b.z, l4b.w};
    float gl[TPL], gl1[TPL];
    #pragma unroll
    for (int j = 0; j < TPL; ++j) {
        const float lm = fmaxf(tanhf(lr[j]), EPS);
        gl[j]  = gamma * lm;          // a_t / (1-d)
        gl1[j] = gamma * (1.f - lm);  // (b_t - r_t) / ((1-d)*v)
    }

    // fully unrolled 1-deep pipeline, named buffers only (no runtime indexing)
    load_row(values, rewards, dones, row0 + 1 * NWAVES, t0, B);
    compute_store(out, row0,              t0, lane, gl, gl1, A);
    load_row(values, rewards, dones, row0 + 2 * NWAVES, t0, A);
    compute_store(out, row0 + 1 * NWAVES, t0, lane, gl, gl1, B);
    load_row(values, rewards, dones, row0 + 3 * NWAVES, t0, B);
    compute_store(out, row0 + 2 * NWAVES, t0, lane, gl, gl1, A);
    compute_store(out, row0 + 3 * NWAVES, t0, lane, gl, gl1, B);
}

extern "C" void kernel_launch(void* const* d_in, const int* in_sizes, int n_in,
                              void* d_out, int out_size, void* d_ws, size_t ws_size,
                              hipStream_t stream) {
    const float* values    = (const float*)d_in[0];
    const float* rewards   = (const float*)d_in[1];
    const float* dones     = (const float*)d_in[2];
    const float* raw_gamma = (const float*)d_in[3];
    const float* raw_lambd = (const float*)d_in[4];
    float* out = (float*)d_out;

    const int block = 256;                    // 4 waves/block
    const int grid  = NWAVES / 4;             // 2048 blocks
    glr_wave_scan11<<<grid, block, 0, stream>>>(
        values, rewards, dones, raw_gamma, raw_lambd, out);
}

// Round 11
// 209.176 us; speedup vs baseline: 1.0424x; 1.0371x over previous
//
#include <hip/hip_runtime.h>

#define BATCH 32768
#define SEQ 512
#define TPL 8          // timesteps per lane (64 lanes * 8 = 512)
#define EPS 1e-8f

typedef float floatx4 __attribute__((ext_vector_type(4)));

// v12 = v9 verbatim (revert; v9 is the measured optimum).
//
// Final evidence table (r0-r10):
//   structure x policy     FETCH   rate    dur
//   v2/3/4/6 (any, normal) 98.9MB  1.95    86-92us
//   v7 (nt-values)         100MB   2.35    72us
//   v9 (nt-all-reads)      100MB   3.01    56.5us   <- best
//   v10/v11 (pipelined)    120MB   2.9-3.0 64-66us
// Bytes pinned: FETCH never below ~99MB across 7 residency/pattern configs
// (r/d miss residual is replacement-lottery at exact-LLC-capacity footprint).
// Rate pinned: 3.0 TB/s across 3 demand structures (pipelining moved it 0%).
// v9 dur == bytes/rate (170MB/3.0 = 56.7 vs 56.5 measured). VALU (21us) fully
// hidden. Both levers individually falsified -> service-rate roofline.
__global__ void __launch_bounds__(256)
glr_wave_scan12(const float* __restrict__ values,
                const float* __restrict__ rewards,
                const float* __restrict__ dones,
                const float* __restrict__ raw_gamma,
                const float* __restrict__ raw_lambd,
                float* __restrict__ out) {
    const int lane = threadIdx.x & 63;
    const int wv   = threadIdx.x >> 6;
    const int row  = blockIdx.x * 4 + wv;
    const int t0   = lane * TPL;

    const float* __restrict__ vrow = values  + (size_t)row * (SEQ + 1);
    const float* __restrict__ rrow = rewards + (size_t)row * SEQ + t0;
    const float* __restrict__ drow = dones   + (size_t)row * SEQ + t0;
    float*       __restrict__ orow = out     + (size_t)row * SEQ + t0;

    // ---- issue ALL independent global loads up front (all dwordx4, all nt) ----
    const floatx4 v4a = __builtin_nontemporal_load((const floatx4*)(vrow + t0));
    const floatx4 v4b = __builtin_nontemporal_load((const floatx4*)(vrow + t0 + 4));
    const floatx4 r4a = __builtin_nontemporal_load((const floatx4*)(rrow));
    const floatx4 r4b = __builtin_nontemporal_load((const floatx4*)(rrow + 4));
    const floatx4 d4a = __builtin_nontemporal_load((const floatx4*)(drow));
    const floatx4 d4b = __builtin_nontemporal_load((const floatx4*)(drow + 4));
    const float4 l4a = *(const float4*)(raw_lambd + t0);
    const float4 l4b = *(const float4*)(raw_lambd + t0 + 4);
    const float vlast = __builtin_nontemporal_load(vrow + SEQ);  // wave-uniform

    const float gamma = fmaxf(tanhf(raw_gamma[0]), EPS);

    // vj[j] = vrow[1 + t0 + j]: shift the aligned pair left by one element,
    // pulling element 8 from the next lane. Lane 63: vrow[512] == vlast.
    const float nx = __shfl_down(v4a.x, 1, 64);
    float vj[TPL] = {v4a.y, v4a.z, v4a.w, v4b.x, v4b.y, v4b.z, v4b.w,
                     (lane == 63) ? vlast : nx};

    float rj[TPL] = {r4a.x, r4a.y, r4a.z, r4a.w, r4b.x, r4b.y, r4b.z, r4b.w};
    float dj[TPL] = {d4a.x, d4a.y, d4a.z, d4a.w, d4b.x, d4b.y, d4b.z, d4b.w};
    const float lr[TPL] = {l4a.x, l4a.y, l4a.z, l4a.w, l4b.x, l4b.y, l4b.z, l4b.w};
    float lm[TPL];
    #pragma unroll
    for (int j = 0; j < TPL; ++j)
        lm[j] = fmaxf(tanhf(lr[j]), EPS);

    // ---- per-lane affine summary (t descending) ----
    float a[TPL], b[TPL];
    float A = 1.f, Bv = 0.f;
    #pragma unroll
    for (int j = TPL - 1; j >= 0; --j) {
        const float g = gamma * (1.f - dj[j]);
        a[j] = g * lm[j];
        b[j] = fmaf(g * (1.f - lm[j]), vj[j], rj[j]);
        Bv = fmaf(a[j], Bv, b[j]);
        A  = a[j] * A;
    }

    // ---- wave-level inclusive suffix scan of (A,B) ----
    #pragma unroll
    for (int dlt = 1; dlt < 64; dlt <<= 1) {
        const float oA = __shfl_down(A, dlt, 64);
        const float oB = __shfl_down(Bv, dlt, 64);
        if (lane + dlt < 64) {                // compose(mine, downstream)
            Bv = fmaf(A, oB, Bv);
            A  = A * oA;
        }
    }
    float EA = __shfl_down(A, 1, 64);
    float EB = __shfl_down(Bv, 1, 64);
    if (lane == 63) { EA = 1.f; EB = 0.f; }

    // ret at this lane's right boundary; values[row][SEQ] is the scan init
    float ret = fmaf(EA, vlast, EB);

    // ---- replay, emit outputs (normal stores; v8 falsified nt-stores) ----
    float o[TPL];
    #pragma unroll
    for (int j = TPL - 1; j >= 0; --j) {
        ret = fmaf(a[j], ret, b[j]);
        o[j] = ret;
    }
    *(float4*)(orow)     = make_float4(o[0], o[1], o[2], o[3]);
    *(float4*)(orow + 4) = make_float4(o[4], o[5], o[6], o[7]);
}

extern "C" void kernel_launch(void* const* d_in, const int* in_sizes, int n_in,
                              void* d_out, int out_size, void* d_ws, size_t ws_size,
                              hipStream_t stream) {
    const float* values    = (const float*)d_in[0];
    const float* rewards   = (const float*)d_in[1];
    const float* dones     = (const float*)d_in[2];
    const float* raw_gamma = (const float*)d_in[3];
    const float* raw_lambd = (const float*)d_in[4];
    float* out = (float*)d_out;

    const int block = 256;                 // 4 waves = 4 rows per block
    const int grid = BATCH / 4;            // 8192 blocks
    glr_wave_scan12<<<grid, block, 0, stream>>>(
        values, rewards, dones, raw_gamma, raw_lambd, out);
}